// Round 3
// baseline (13.190 us; speedup 1.0000x reference)
//
#include <hip/hip_runtime.h>
#include <hip/hip_bf16.h>

// out[l,m,p,o] = sum_{k,j,i} w[k,j,l,m,i] * s[2*(l+k-1)+j, p, (o+i-2) mod 56]
//   s[c,p,q] = x[c,p,q] + x[c+64,p,q]
//   contribution valid iff 0 <= l+k-1 < 32 and 0 <= o+i-1 < 56
// final[l*4+m, (p+1)%56, o] = out[l,m,p,o]
//
// Shuffle version: no LDS tile, no barrier. Each lane owns column o = lane;
// neighbor columns (o-1, o-2 with the mod-56 roll) come from ds_bpermute.
// Each thread computes 2 m-outputs to amortize the 6 s-loads over 36 FMAs.
__global__ __launch_bounds__(256) void fused_unfold_einsum(
    const float* __restrict__ x,   // (128, 56, 56)
    const float* __restrict__ w,   // (3, 2, 32, 4, 3)
    float* __restrict__ out)       // (128, 56, 56)
{
    const int pg = blockIdx.x;          // 0..13
    const int bz = blockIdx.y;          // 0..63 = l*2 + mh
    const int l  = bz >> 1;             // 0..31 (uniform)
    const int mh = bz & 1;              // 0..1  (uniform) -> m = 2*mh, 2*mh+1
    const int tid  = threadIdx.x;
    const int po   = tid >> 6;          // 0..3 (wave-uniform)
    const int o    = tid & 63;          // 0..63; outputs exist for o < 56
    const int p    = pg * 4 + po;       // 0..55
    const int row  = p * 56;

    // shuffle source lanes (q-columns after folding the roll):
    //   i=2 -> q = o        (valid o <= 54)
    //   i=1 -> q = o-1, o==0 wraps to 55 (always valid)
    //   i=0 -> q = o-2, o==1 wraps to 55 (valid o >= 1)
    const int  src1 = (o == 0) ? 55 : o - 1;
    const int  src0 = (o >= 2) ? o - 2 : 55;
    const bool v0ok = (o >= 1);
    const bool v2ok = (o <= 54);
    const int  col  = (o < 56) ? o : 55;   // lanes 56..63 load a safe dup

    float acc0 = 0.f, acc1 = 0.f;

    #pragma unroll
    for (int kk = 0; kk < 3; ++kk) {
        const int lsrc = l - 1 + kk;           // uniform
        if (lsrc < 0 || lsrc >= 32) continue;  // scalar branch, no divergence
        #pragma unroll
        for (int j = 0; j < 2; ++j) {
            const float* b = x + (2 * lsrc + j) * 3136 + row + col;
            const float s = b[0] + b[64 * 3136];

            float v0 = __shfl(s, src0, 64);
            const float v1 = __shfl(s, src1, 64);
            if (!v0ok) v0 = 0.f;
            const float v2 = v2ok ? s : 0.f;

            // w[k,j,l,m,i] at ((k*2+j)*32 + l)*12 + m*3 + i   (uniform base)
            const float* wp = w + ((kk * 2 + j) * 32 + l) * 12 + mh * 6;
            acc0 = fmaf(wp[0], v0, fmaf(wp[1], v1, fmaf(wp[2], v2, acc0)));
            acc1 = fmaf(wp[3], v0, fmaf(wp[4], v1, fmaf(wp[5], v2, acc1)));
        }
    }

    if (o < 56) {
        const int p_out = (p + 1 == 56) ? 0 : (p + 1);
        float* obase = out + ((l * 4 + mh * 2) * 56 + p_out) * 56 + o;
        obase[0]    = acc0;
        obase[3136] = acc1;
    }
}

extern "C" void kernel_launch(void* const* d_in, const int* in_sizes, int n_in,
                              void* d_out, int out_size, void* d_ws, size_t ws_size,
                              hipStream_t stream) {
    const float* x = (const float*)d_in[0];
    const float* w = (const float*)d_in[1];
    float* out = (float*)d_out;

    dim3 grid(14, 64);    // (p-groups, l*2 + m-half)
    dim3 block(256);      // 4 p-rows x 64 lanes (56 produce outputs)
    fused_unfold_einsum<<<grid, block, 0, stream>>>(x, w, out);
}

// Round 4
// 9.836 us; speedup vs baseline: 1.3410x; 1.3410x over previous
//
#include <hip/hip_runtime.h>
#include <hip/hip_bf16.h>

// out[l,m,p,o] = sum_{k,j,i} w[k,j,l,m,i] * s[2*(l+k-1)+j, p, (o+i-2) mod 56]
//   s[c,p,q] = x[c,p,q] + x[c+64,p,q]
//   contribution valid iff 0 <= l+k-1 < 32 and 0 <= o+i-1 < 56
// final[l*4+m, (p+1)%56, o] = out[l,m,p,o]
//
// Barrier-free: each wave (po) stages its OWN 6x56 strip of s into a private
// LDS row, so ds_write -> ds_read ordering within the wave (lgkmcnt) is the
// only sync needed. Grid (14, 128) = 1792 blocks x 4 waves = 28 waves/CU.
__global__ __launch_bounds__(256) void fused_unfold_einsum(
    const float* __restrict__ x,   // (128, 56, 56)
    const float* __restrict__ w,   // (3, 2, 32, 4, 3)
    float* __restrict__ out)       // (128, 56, 56)
{
    __shared__ __align__(16) float sblk[4][6][64];   // [po][ch][q], wave-private rows

    const int pg = blockIdx.x;          // 0..13
    const int lm = blockIdx.y;          // 0..127
    const int l  = lm >> 2;             // 0..31 (uniform)
    const int m  = lm & 3;              // 0..3  (uniform)
    const int tid  = threadIdx.x;
    const int lane = tid & 63;
    const int po   = tid >> 6;          // 0..3 (wave-uniform)
    const int p    = pg * 4 + po;       // 0..55

    float* const strip = &sblk[po][0][0];   // this wave's 6x64 strip

    // ---- stage this wave's strip: 6 channels x 14 float4 = 84 slots ----
    #pragma unroll
    for (int it = 0; it < 2; ++it) {
        const int slot = it * 64 + lane;
        if (slot < 84) {
            const int ch = slot / 14;          // 0..5  (= kk*2 + j)
            const int q4 = slot - ch * 14;     // 0..13
            const int lsrc = l - 1 + (ch >> 1);
            float4 v = make_float4(0.f, 0.f, 0.f, 0.f);
            if ((unsigned)lsrc < 32u) {
                const float* bptr = x + (2 * lsrc + (ch & 1)) * 3136 + p * 56 + q4 * 4;
                const float4 a = *(const float4*)bptr;
                const float4 b = *(const float4*)(bptr + 64 * 3136);
                v = make_float4(a.x + b.x, a.y + b.y, a.z + b.z, a.w + b.w);
            }
            *(float4*)(strip + ch * 64 + q4 * 4) = v;
        }
    }
    // no __syncthreads(): each wave reads only what it wrote (lgkmcnt ordering)

    // ---- compute: lane o -> output (l,m,p,o) ----
    const int o = lane;
    if (o >= 56) return;

    const int q0 = (o >= 2) ? (o - 2) : 55;   // i=0 src (o==1 wraps to 55; o==0 unused)
    const int q1 = (o >= 1) ? (o - 1) : 55;   // i=1 src (o==0 wraps to 55)
    const int q2 = o;                         // i=2 src
    const bool v0ok = (o >= 1);
    const bool v2ok = (o <= 54);

    float acc = 0.f;
    #pragma unroll
    for (int ch = 0; ch < 6; ++ch) {
        const float* row = strip + ch * 64;
        const float v0 = v0ok ? row[q0] : 0.f;
        const float v1 = row[q1];
        const float v2 = v2ok ? row[q2] : 0.f;
        const float* wp = w + (ch * 32 + l) * 12 + m * 3;   // uniform -> s_load
        acc = fmaf(wp[0], v0, fmaf(wp[1], v1, fmaf(wp[2], v2, acc)));
    }

    const int p_out = (p + 1 == 56) ? 0 : (p + 1);
    out[((l * 4 + m) * 56 + p_out) * 56 + o] = acc;
}

extern "C" void kernel_launch(void* const* d_in, const int* in_sizes, int n_in,
                              void* d_out, int out_size, void* d_ws, size_t ws_size,
                              hipStream_t stream) {
    const float* x = (const float*)d_in[0];
    const float* w = (const float*)d_in[1];
    float* out = (float*)d_out;

    dim3 grid(14, 128);   // (p-groups, l*4+m)
    dim3 block(256);      // 4 waves; each wave owns one p-row
    fused_unfold_einsum<<<grid, block, 0, stream>>>(x, w, out);
}